// Round 2
// baseline (250.642 us; speedup 1.0000x reference)
//
#include <hip/hip_runtime.h>
#include <stdint.h>

#define NS 10
#define DIM 512
#define NQ 4096
#define NP 1024

typedef unsigned short ushort_t;
typedef __bf16 bf16el_t;
typedef bf16el_t bf16x8 __attribute__((ext_vector_type(8)));
typedef float floatx4 __attribute__((ext_vector_type(4)));

// ================= threefry2x32-20 (JAX-compatible, partitionable path) =================
__host__ __device__ __forceinline__ uint32_t rotl32(uint32_t x, int r) {
  return (x << r) | (x >> (32 - r));
}

__host__ __device__ __forceinline__ void threefry2x32(uint32_t k0, uint32_t k1,
                                                      uint32_t x0, uint32_t x1,
                                                      uint32_t* o0, uint32_t* o1) {
  uint32_t ks2 = k0 ^ k1 ^ 0x1BD11BDAu;
  x0 += k0; x1 += k1;
#define TF_R(r) { x0 += x1; x1 = rotl32(x1, r); x1 ^= x0; }
  TF_R(13) TF_R(15) TF_R(26) TF_R(6)   x0 += k1;  x1 += ks2 + 1u;
  TF_R(17) TF_R(29) TF_R(16) TF_R(24)  x0 += ks2; x1 += k0 + 2u;
  TF_R(13) TF_R(15) TF_R(26) TF_R(6)   x0 += k0;  x1 += k1 + 3u;
  TF_R(17) TF_R(29) TF_R(16) TF_R(24)  x0 += k1;  x1 += ks2 + 4u;
  TF_R(13) TF_R(15) TF_R(26) TF_R(6)   x0 += ks2; x1 += k0 + 5u;
#undef TF_R
  *o0 = x0; *o1 = x1;
}

__device__ __forceinline__ uint32_t jax_random_bits(uint32_t k0, uint32_t k1, uint32_t idx) {
  uint32_t o0, o1;
  threefry2x32(k0, k1, 0u, idx, &o0, &o1);
  return o0 ^ o1;
}

// XLA ErfInv32 (Giles polynomial)
__device__ __forceinline__ float erfinvf_xla(float x) {
  float w = -log1pf(-x * x);
  float p;
  if (w < 5.0f) {
    w -= 2.5f;
    p = 2.81022636e-08f;
    p = fmaf(p, w, 3.43273939e-07f);
    p = fmaf(p, w, -3.5233877e-06f);
    p = fmaf(p, w, -4.39150654e-06f);
    p = fmaf(p, w, 0.00021858087f);
    p = fmaf(p, w, -0.00125372503f);
    p = fmaf(p, w, -0.00417768164f);
    p = fmaf(p, w, 0.246640727f);
    p = fmaf(p, w, 1.50140941f);
  } else {
    w = sqrtf(w) - 3.0f;
    p = -0.000200214257f;
    p = fmaf(p, w, 0.000100950558f);
    p = fmaf(p, w, 0.00134934322f);
    p = fmaf(p, w, -0.00367342844f);
    p = fmaf(p, w, 0.00573950773f);
    p = fmaf(p, w, -0.0076224613f);
    p = fmaf(p, w, 0.00943887047f);
    p = fmaf(p, w, 1.00167406f);
    p = fmaf(p, w, 2.83297682f);
  }
  return p * x;
}

__device__ __forceinline__ float jax_bits_to_normal(uint32_t bits) {
  float f = __uint_as_float((bits >> 9) | 0x3F800000u) - 1.0f;
  float u = f * 2.0f - 0.99999994f;
  u = fmaxf(u, -0.99999994f);
  return 1.41421356f * erfinvf_xla(u);
}

__device__ __forceinline__ float softplusf(float x) { return log1pf(expf(x)); }

__device__ __forceinline__ float bf2f(ushort_t u) {
  return __uint_as_float(((uint32_t)u) << 16);
}
__device__ __forceinline__ ushort_t f2bf(float f) {
  uint32_t u = __float_as_uint(f);
  u += 0x7FFFu + ((u >> 16) & 1u);
  return (ushort_t)(u >> 16);
}

// async global->LDS, 16B per lane. LDS dst = wave-uniform base + lane*16.
__device__ __forceinline__ void gll16(const void* g, void* l) {
  __builtin_amdgcn_global_load_lds(
      (const __attribute__((address_space(1))) uint32_t*)g,
      (__attribute__((address_space(3))) uint32_t*)l, 16, 0, 0);
}

// ================= sampling / conversion kernels =================

// wt[s][e][k] = bf16( mu[k][e] + softplus(rho[k][e]) * eps_w[s][k][e] )   (W transposed)
__global__ __launch_bounds__(256) void gen_w_kernel(const float* __restrict__ wmu,
                                                    const float* __restrict__ wrho,
                                                    ushort_t* __restrict__ wt,
                                                    uint32_t kw0, uint32_t kw1) {
  uint32_t tid = blockIdx.x * 256u + threadIdx.x;
  uint32_t s = tid >> 18;
  uint32_t r = tid & 0x3FFFFu;
  uint32_t e = r >> 9;
  uint32_t k = r & 511u;
  uint32_t eps_idx = (s << 18) | (k << 9) | e;      // JAX order [s][k][e]
  uint32_t bits = jax_random_bits(kw0, kw1, eps_idx);
  float n = jax_bits_to_normal(bits);
  uint32_t mi = (k << 9) | e;
  float w = wmu[mi] + softplusf(wrho[mi]) * n;
  wt[tid] = f2bf(w);
}

__global__ __launch_bounds__(256) void gen_b_kernel(const float* __restrict__ bmu,
                                                    const float* __restrict__ brho,
                                                    float* __restrict__ bvec,
                                                    uint32_t kb0, uint32_t kb1) {
  uint32_t tid = blockIdx.x * 256u + threadIdx.x;   // 5120
  uint32_t e = tid & 511u;
  uint32_t bits = jax_random_bits(kb0, kb1, tid);
  float n = jax_bits_to_normal(bits);
  bvec[tid] = bmu[e] + softplusf(brho[e]) * n;
}

__global__ __launch_bounds__(256) void cvt_q_kernel(const float* __restrict__ qf,
                                                    ushort_t* __restrict__ qb) {
  int i = (blockIdx.x * 256 + threadIdx.x) * 4;
  float4 v = *(const float4*)&qf[i];
  uint2 r;
  r.x = (uint32_t)f2bf(v.x) | ((uint32_t)f2bf(v.y) << 16);
  r.y = (uint32_t)f2bf(v.z) | ((uint32_t)f2bf(v.w) << 16);
  *(uint2*)&qb[i] = r;
}

__global__ __launch_bounds__(64) void cvt_p_sqp_kernel(const float* __restrict__ pf,
                                                       ushort_t* __restrict__ pb,
                                                       float* __restrict__ sqp) {
  int p = blockIdx.x;
  int lane = threadIdx.x;
  const float* src = pf + p * DIM + lane * 8;
  float4 a = *(const float4*)src;
  float4 b = *(const float4*)(src + 4);
  float vals[8] = {a.x, a.y, a.z, a.w, b.x, b.y, b.z, b.w};
  ushort_t o[8];
  float ss = 0.f;
#pragma unroll
  for (int i = 0; i < 8; ++i) {
    o[i] = f2bf(vals[i]);
    float f = bf2f(o[i]);
    ss += f * f;
  }
  *(uint4*)&pb[p * DIM + lane * 8] = *(const uint4*)o;
#pragma unroll
  for (int off = 32; off; off >>= 1) ss += __shfl_xor(ss, off, 64);
  if (lane == 0) sqp[p] = ss;
}

// ================= GEMM1: tq[s] = q @ W_s + b_s  (m97 structure) =================
// 128x128 tile, BK=64, global_load_lds, 4 waves of 64x64. grid (32,4,10).
__global__ __launch_bounds__(256) void gemm_tq_kernel(const ushort_t* __restrict__ qb,
                                                      const ushort_t* __restrict__ wt,
                                                      const float* __restrict__ bvec,
                                                      ushort_t* __restrict__ tq) {
  __shared__ __align__(16) ushort_t lsA[128 * 64];
  __shared__ __align__(16) ushort_t lsB[128 * 64];
  const int lane = threadIdx.x & 63;
  const int wave = threadIdx.x >> 6;
  const int wm = wave >> 1, wn = wave & 1;   // 2x2 wave grid, 64x64 each
  const int qBase = blockIdx.x * 128;
  const int eBase = blockIdx.y * 128;
  const int s = blockIdx.z;
  const ushort_t* wbase = wt + (size_t)s * (DIM * DIM);  // [e][k]
  // staging addresses: wave loads 32 rows of each tile via 4 calls of 8 rows
  const int srow = lane >> 3;            // 0..7
  const int scol = (lane & 7) * 16;      // bytes within 128B k-chunk
  const char* gA = (const char*)qb + (size_t)(qBase + wave * 32 + srow) * (DIM * 2) + scol;
  const char* gB = (const char*)wbase + (size_t)(eBase + wave * 32 + srow) * (DIM * 2) + scol;
  char* lA = (char*)&lsA[wave * 32 * 64];
  char* lB = (char*)&lsB[wave * 32 * 64];
  const int cn = lane & 15;
  const int kq = (lane >> 4) * 8;
  const floatx4 fzero = {0.f, 0.f, 0.f, 0.f};
  floatx4 acc[4][4];
#pragma unroll
  for (int mi = 0; mi < 4; ++mi)
#pragma unroll
    for (int ni = 0; ni < 4; ++ni) acc[mi][ni] = fzero;

  for (int kt = 0; kt < 8; ++kt) {
    __syncthreads();
#pragma unroll
    for (int j = 0; j < 4; ++j) {
      gll16(gA + (size_t)j * 8 * (DIM * 2), lA + j * 1024);
      gll16(gB + (size_t)j * 8 * (DIM * 2), lB + j * 1024);
    }
    gA += 128; gB += 128;
    __syncthreads();
#pragma unroll
    for (int kk = 0; kk < 64; kk += 32) {
      bf16x8 aF[4], bF[4];
#pragma unroll
      for (int mi = 0; mi < 4; ++mi)
        aF[mi] = *(const bf16x8*)&lsA[(wm * 64 + mi * 16 + cn) * 64 + kk + kq];
#pragma unroll
      for (int ni = 0; ni < 4; ++ni)
        bF[ni] = *(const bf16x8*)&lsB[(wn * 64 + ni * 16 + cn) * 64 + kk + kq];
#pragma unroll
      for (int mi = 0; mi < 4; ++mi)
#pragma unroll
        for (int ni = 0; ni < 4; ++ni)
          acc[mi][ni] = __builtin_amdgcn_mfma_f32_16x16x32_bf16(aF[mi], bF[ni], acc[mi][ni], 0, 0, 0);
    }
  }
  const int rq = (lane >> 4) * 4;
#pragma unroll
  for (int ni = 0; ni < 4; ++ni) {
    const int e = eBase + wn * 64 + ni * 16 + cn;
    const float bv = bvec[s * DIM + e];
#pragma unroll
    for (int mi = 0; mi < 4; ++mi)
#pragma unroll
      for (int r = 0; r < 4; ++r) {
        const int q = qBase + wm * 64 + mi * 16 + rq + r;
        tq[(size_t)s * (NQ * DIM) + (size_t)q * DIM + e] = f2bf(acc[mi][ni][r] + bv);
      }
  }
}

// ================= sq_q: 16 lanes per row =================
__global__ __launch_bounds__(256) void sqq_kernel(const ushort_t* __restrict__ tq,
                                                  float* __restrict__ sqq) {
  int tid = blockIdx.x * 256 + threadIdx.x;
  int row = tid >> 4;
  int sub = tid & 15;
  const ushort_t* rp = tq + (size_t)row * DIM + sub * 32;
  float ss = 0.f;
#pragma unroll
  for (int i = 0; i < 4; ++i) {
    uint4 v = ((const uint4*)rp)[i];
    uint32_t wsv[4] = {v.x, v.y, v.z, v.w};
#pragma unroll
    for (int j = 0; j < 4; ++j) {
      float lo = bf2f((ushort_t)(wsv[j] & 0xFFFFu));
      float hi = bf2f((ushort_t)(wsv[j] >> 16));
      ss += lo * lo + hi * hi;
    }
  }
#pragma unroll
  for (int off = 8; off; off >>= 1) ss += __shfl_xor(ss, off, 64);
  if (sub == 0) sqq[row] = ss;
}

// ================= GEMM2 fused dist/mean/std =================
// 64q x 128p tile, BK=64, global_load_lds, 4 waves of 32x64, s-loop inside. grid (64,8).
__global__ __launch_bounds__(256) void gemm_dist_kernel(const ushort_t* __restrict__ tq,
                                                        const ushort_t* __restrict__ pb,
                                                        const float* __restrict__ sqq,
                                                        const float* __restrict__ sqp,
                                                        float* __restrict__ out) {
  __shared__ __align__(16) ushort_t lsA[64 * 64];
  __shared__ __align__(16) ushort_t lsB[128 * 64];
  const int lane = threadIdx.x & 63;
  const int wave = threadIdx.x >> 6;
  const int wm = wave >> 1;            // q offset 32*wm
  const int wn = wave & 1;             // p offset 64*wn
  const int qBase = blockIdx.x * 64;
  const int pBase = blockIdx.y * 128;
  const int srow = lane >> 3;
  const int scol = (lane & 7) * 16;
  // A: 64 rows -> wave loads 16 rows (2 calls); B: 128 rows -> 32 rows (4 calls)
  const char* gA = (const char*)tq + (size_t)(qBase + wave * 16 + srow) * (DIM * 2) + scol;
  const char* gB = (const char*)pb + (size_t)(pBase + wave * 32 + srow) * (DIM * 2) + scol;
  char* lA = (char*)&lsA[wave * 16 * 64];
  char* lB = (char*)&lsB[wave * 32 * 64];
  const int cn = lane & 15;
  const int kq = (lane >> 4) * 8;
  const int rq = (lane >> 4) * 4;
  const floatx4 fzero = {0.f, 0.f, 0.f, 0.f};

  float sum[2][4][4] = {};
  float ssq[2][4][4] = {};
  float sqp_v[4];
#pragma unroll
  for (int ni = 0; ni < 4; ++ni) sqp_v[ni] = sqp[pBase + wn * 64 + ni * 16 + cn];

  for (int s = 0; s < NS; ++s) {
    floatx4 acc[2][4];
#pragma unroll
    for (int mi = 0; mi < 2; ++mi)
#pragma unroll
      for (int ni = 0; ni < 4; ++ni) acc[mi][ni] = fzero;

    for (int kt = 0; kt < 8; ++kt) {
      __syncthreads();
      gll16(gA, lA);
      gll16(gA + (size_t)8 * (DIM * 2), lA + 1024);
#pragma unroll
      for (int j = 0; j < 4; ++j)
        gll16(gB + (size_t)j * 8 * (DIM * 2), lB + j * 1024);
      gA += 128; gB += 128;
      __syncthreads();
#pragma unroll
      for (int kk = 0; kk < 64; kk += 32) {
        bf16x8 aF[2], bF[4];
#pragma unroll
        for (int mi = 0; mi < 2; ++mi)
          aF[mi] = *(const bf16x8*)&lsA[(wm * 32 + mi * 16 + cn) * 64 + kk + kq];
#pragma unroll
        for (int ni = 0; ni < 4; ++ni)
          bF[ni] = *(const bf16x8*)&lsB[(wn * 64 + ni * 16 + cn) * 64 + kk + kq];
#pragma unroll
        for (int mi = 0; mi < 2; ++mi)
#pragma unroll
          for (int ni = 0; ni < 4; ++ni)
            acc[mi][ni] = __builtin_amdgcn_mfma_f32_16x16x32_bf16(aF[mi], bF[ni], acc[mi][ni], 0, 0, 0);
      }
    }
    gA += (size_t)NQ * DIM * 2 - 1024;   // next sample, rewind k
    gB -= 1024;                           // rewind k
    // fold sample s into running stats
#pragma unroll
    for (int mi = 0; mi < 2; ++mi) {
      float4 aqv = *(const float4*)&sqq[s * NQ + qBase + wm * 32 + mi * 16 + rq];
      float aqa[4] = {aqv.x, aqv.y, aqv.z, aqv.w};
#pragma unroll
      for (int r = 0; r < 4; ++r) {
        float aq = aqa[r];
#pragma unroll
        for (int ni = 0; ni < 4; ++ni) {
          float c = acc[mi][ni][r];
          float dd = sqrtf(fmaxf(aq + sqp_v[ni] - 2.0f * c, 1e-12f));
          sum[mi][ni][r] += dd;
          ssq[mi][ni][r] += dd * dd;
        }
      }
    }
  }
#pragma unroll
  for (int mi = 0; mi < 2; ++mi)
#pragma unroll
    for (int ni = 0; ni < 4; ++ni)
#pragma unroll
      for (int r = 0; r < 4; ++r) {
        int q = qBase + wm * 32 + mi * 16 + rq + r;
        int p = pBase + wn * 64 + ni * 16 + cn;
        float sm = sum[mi][ni][r];
        float mean = sm * 0.1f;
        float var = (ssq[mi][ni][r] - sm * sm * 0.1f) * (1.0f / 9.0f);
        out[(size_t)q * NP + p] = mean;
        out[(size_t)NQ * NP + (size_t)q * NP + p] = sqrtf(fmaxf(var, 0.0f));
      }
}

// ================= launch =================
extern "C" void kernel_launch(void* const* d_in, const int* in_sizes, int n_in,
                              void* d_out, int out_size, void* d_ws, size_t ws_size,
                              hipStream_t stream) {
  const float* qf   = (const float*)d_in[0];
  const float* pf   = (const float*)d_in[1];
  const float* wmu  = (const float*)d_in[2];
  const float* wrho = (const float*)d_in[3];
  const float* bmu  = (const float*)d_in[4];
  const float* brho = (const float*)d_in[5];
  float* out = (float*)d_out;
  char* ws = (char*)d_ws;
  ushort_t* wt   = (ushort_t*)(ws);              //  5,242,880  W^T bf16 [s][e][k]
  ushort_t* qb   = (ushort_t*)(ws + 5242880);    //  4,194,304  query bf16
  ushort_t* pb   = (ushort_t*)(ws + 9437184);    //  1,048,576  proto bf16
  float*    bvec = (float*)   (ws + 10485760);   //     20,480  bias samples
  float*    sqp  = (float*)   (ws + 10506240);   //      4,096  ||p||^2
  ushort_t* tq   = (ushort_t*)(ws + 10510336);   // 41,943,040  tq bf16 [s][q][e]
  float*    sqq  = (float*)   (ws + 52453376);   //    163,840  ||tq||^2

  uint32_t kw0, kw1, kb0, kb1;
  threefry2x32(0u, 42u, 0u, 0u, &kw0, &kw1);
  threefry2x32(0u, 42u, 0u, 1u, &kb0, &kb1);

  hipLaunchKernelGGL(gen_w_kernel, dim3(10240), dim3(256), 0, stream, wmu, wrho, wt, kw0, kw1);
  hipLaunchKernelGGL(gen_b_kernel, dim3(20), dim3(256), 0, stream, bmu, brho, bvec, kb0, kb1);
  hipLaunchKernelGGL(cvt_q_kernel, dim3(2048), dim3(256), 0, stream, qf, qb);
  hipLaunchKernelGGL(cvt_p_sqp_kernel, dim3(1024), dim3(64), 0, stream, pf, pb, sqp);
  hipLaunchKernelGGL(gemm_tq_kernel, dim3(32, 4, 10), dim3(256), 0, stream, qb, wt, bvec, tq);
  hipLaunchKernelGGL(sqq_kernel, dim3(2560), dim3(256), 0, stream, tq, sqq);
  hipLaunchKernelGGL(gemm_dist_kernel, dim3(64, 8), dim3(256), 0, stream, tq, pb, sqq, sqp, out);
}

// Round 3
// 226.226 us; speedup vs baseline: 1.1079x; 1.1079x over previous
//
#include <hip/hip_runtime.h>
#include <stdint.h>

#define NS 10
#define DIM 512
#define NQ 4096
#define NP 1024

typedef unsigned short ushort_t;
typedef __bf16 bf16el_t;
typedef bf16el_t bf16x8 __attribute__((ext_vector_type(8)));
typedef float floatx4 __attribute__((ext_vector_type(4)));

// ================= threefry2x32-20 (JAX-compatible, partitionable path) =================
__host__ __device__ __forceinline__ uint32_t rotl32(uint32_t x, int r) {
  return (x << r) | (x >> (32 - r));
}

__host__ __device__ __forceinline__ void threefry2x32(uint32_t k0, uint32_t k1,
                                                      uint32_t x0, uint32_t x1,
                                                      uint32_t* o0, uint32_t* o1) {
  uint32_t ks2 = k0 ^ k1 ^ 0x1BD11BDAu;
  x0 += k0; x1 += k1;
#define TF_R(r) { x0 += x1; x1 = rotl32(x1, r); x1 ^= x0; }
  TF_R(13) TF_R(15) TF_R(26) TF_R(6)   x0 += k1;  x1 += ks2 + 1u;
  TF_R(17) TF_R(29) TF_R(16) TF_R(24)  x0 += ks2; x1 += k0 + 2u;
  TF_R(13) TF_R(15) TF_R(26) TF_R(6)   x0 += k0;  x1 += k1 + 3u;
  TF_R(17) TF_R(29) TF_R(16) TF_R(24)  x0 += k1;  x1 += ks2 + 4u;
  TF_R(13) TF_R(15) TF_R(26) TF_R(6)   x0 += ks2; x1 += k0 + 5u;
#undef TF_R
  *o0 = x0; *o1 = x1;
}

__device__ __forceinline__ uint32_t jax_random_bits(uint32_t k0, uint32_t k1, uint32_t idx) {
  uint32_t o0, o1;
  threefry2x32(k0, k1, 0u, idx, &o0, &o1);
  return o0 ^ o1;
}

// XLA ErfInv32 (Giles polynomial)
__device__ __forceinline__ float erfinvf_xla(float x) {
  float w = -log1pf(-x * x);
  float p;
  if (w < 5.0f) {
    w -= 2.5f;
    p = 2.81022636e-08f;
    p = fmaf(p, w, 3.43273939e-07f);
    p = fmaf(p, w, -3.5233877e-06f);
    p = fmaf(p, w, -4.39150654e-06f);
    p = fmaf(p, w, 0.00021858087f);
    p = fmaf(p, w, -0.00125372503f);
    p = fmaf(p, w, -0.00417768164f);
    p = fmaf(p, w, 0.246640727f);
    p = fmaf(p, w, 1.50140941f);
  } else {
    w = sqrtf(w) - 3.0f;
    p = -0.000200214257f;
    p = fmaf(p, w, 0.000100950558f);
    p = fmaf(p, w, 0.00134934322f);
    p = fmaf(p, w, -0.00367342844f);
    p = fmaf(p, w, 0.00573950773f);
    p = fmaf(p, w, -0.0076224613f);
    p = fmaf(p, w, 0.00943887047f);
    p = fmaf(p, w, 1.00167406f);
    p = fmaf(p, w, 2.83297682f);
  }
  return p * x;
}

__device__ __forceinline__ float jax_bits_to_normal(uint32_t bits) {
  float f = __uint_as_float((bits >> 9) | 0x3F800000u) - 1.0f;
  float u = f * 2.0f - 0.99999994f;
  u = fmaxf(u, -0.99999994f);
  return 1.41421356f * erfinvf_xla(u);
}

__device__ __forceinline__ float softplusf(float x) { return log1pf(expf(x)); }

__device__ __forceinline__ float bf2f(ushort_t u) {
  return __uint_as_float(((uint32_t)u) << 16);
}
__device__ __forceinline__ ushort_t f2bf(float f) {
  uint32_t u = __float_as_uint(f);
  u += 0x7FFFu + ((u >> 16) & 1u);
  return (ushort_t)(u >> 16);
}

// async global->LDS, 16B per lane. LDS dst = wave-uniform base + lane*16.
__device__ __forceinline__ void gll16(const void* g, void* l) {
  __builtin_amdgcn_global_load_lds(
      (const __attribute__((address_space(1))) uint32_t*)g,
      (__attribute__((address_space(3))) uint32_t*)l, 16, 0, 0);
}

// ================= sampling / conversion kernels =================

// wt[s][e][k] = bf16( mu[k][e] + softplus(rho[k][e]) * eps_w[s][k][e] )   (W transposed)
__global__ __launch_bounds__(256) void gen_w_kernel(const float* __restrict__ wmu,
                                                    const float* __restrict__ wrho,
                                                    ushort_t* __restrict__ wt,
                                                    uint32_t kw0, uint32_t kw1) {
  uint32_t tid = blockIdx.x * 256u + threadIdx.x;
  uint32_t s = tid >> 18;
  uint32_t r = tid & 0x3FFFFu;
  uint32_t e = r >> 9;
  uint32_t k = r & 511u;
  uint32_t eps_idx = (s << 18) | (k << 9) | e;      // JAX order [s][k][e]
  uint32_t bits = jax_random_bits(kw0, kw1, eps_idx);
  float n = jax_bits_to_normal(bits);
  uint32_t mi = (k << 9) | e;
  float w = wmu[mi] + softplusf(wrho[mi]) * n;
  wt[tid] = f2bf(w);
}

__global__ __launch_bounds__(256) void gen_b_kernel(const float* __restrict__ bmu,
                                                    const float* __restrict__ brho,
                                                    float* __restrict__ bvec,
                                                    uint32_t kb0, uint32_t kb1) {
  uint32_t tid = blockIdx.x * 256u + threadIdx.x;   // 5120
  uint32_t e = tid & 511u;
  uint32_t bits = jax_random_bits(kb0, kb1, tid);
  float n = jax_bits_to_normal(bits);
  bvec[tid] = bmu[e] + softplusf(brho[e]) * n;
}

__global__ __launch_bounds__(256) void cvt_q_kernel(const float* __restrict__ qf,
                                                    ushort_t* __restrict__ qb) {
  int i = (blockIdx.x * 256 + threadIdx.x) * 4;
  float4 v = *(const float4*)&qf[i];
  uint2 r;
  r.x = (uint32_t)f2bf(v.x) | ((uint32_t)f2bf(v.y) << 16);
  r.y = (uint32_t)f2bf(v.z) | ((uint32_t)f2bf(v.w) << 16);
  *(uint2*)&qb[i] = r;
}

__global__ __launch_bounds__(64) void cvt_p_sqp_kernel(const float* __restrict__ pf,
                                                       ushort_t* __restrict__ pb,
                                                       float* __restrict__ sqp) {
  int p = blockIdx.x;
  int lane = threadIdx.x;
  const float* src = pf + p * DIM + lane * 8;
  float4 a = *(const float4*)src;
  float4 b = *(const float4*)(src + 4);
  float vals[8] = {a.x, a.y, a.z, a.w, b.x, b.y, b.z, b.w};
  ushort_t o[8];
  float ss = 0.f;
#pragma unroll
  for (int i = 0; i < 8; ++i) {
    o[i] = f2bf(vals[i]);
    float f = bf2f(o[i]);
    ss += f * f;
  }
  *(uint4*)&pb[p * DIM + lane * 8] = *(const uint4*)o;
#pragma unroll
  for (int off = 32; off; off >>= 1) ss += __shfl_xor(ss, off, 64);
  if (lane == 0) sqp[p] = ss;
}

// ===== XOR-swizzled LDS tile layout =====
// Tile row = 64 bf16 = 128 B = 8 chunks of 16 B. Physical chunk p of row r holds
// logical chunk p ^ (r & 7).  Staging covers 8-row-aligned groups, so lane ℓ
// (srow=ℓ>>3, scc=ℓ&7) fetches global chunk scc ^ srow  -> constant per lane.
// Fragment read of logical chunk j at row r is at r*128 + ((j ^ (r&7))*16);
// all row bases are multiples of 8, so r&7 == cn&7.

// ================= GEMM1: tq[s] = q @ W_s + b_s =================
// 128x128 tile, BK=64, global_load_lds + swizzle, 4 waves of 64x64. grid (32,4,10).
__global__ __launch_bounds__(256) void gemm_tq_kernel(const ushort_t* __restrict__ qb,
                                                      const ushort_t* __restrict__ wt,
                                                      const float* __restrict__ bvec,
                                                      ushort_t* __restrict__ tq) {
  __shared__ __align__(16) ushort_t lsA[128 * 64];
  __shared__ __align__(16) ushort_t lsB[128 * 64];
  const int lane = threadIdx.x & 63;
  const int wave = threadIdx.x >> 6;
  const int wm = wave >> 1, wn = wave & 1;   // 2x2 wave grid, 64x64 each
  const int qBase = blockIdx.x * 128;
  const int eBase = blockIdx.y * 128;
  const int s = blockIdx.z;
  const ushort_t* wbase = wt + (size_t)s * (DIM * DIM);  // [e][k]
  const int srow = lane >> 3;                       // 0..7
  const int scol = ((lane & 7) ^ srow) * 16;        // swizzled global chunk (bytes)
  const char* gA = (const char*)qb + (size_t)(qBase + wave * 32 + srow) * (DIM * 2) + scol;
  const char* gB = (const char*)wbase + (size_t)(eBase + wave * 32 + srow) * (DIM * 2) + scol;
  char* lA = (char*)&lsA[wave * 32 * 64];
  char* lB = (char*)&lsB[wave * 32 * 64];
  const int cn = lane & 15;
  const int cn7 = cn & 7;
  const int jc = lane >> 4;                         // 0..3 (chunk sub-index)
  const floatx4 fzero = {0.f, 0.f, 0.f, 0.f};
  floatx4 acc[4][4];
#pragma unroll
  for (int mi = 0; mi < 4; ++mi)
#pragma unroll
    for (int ni = 0; ni < 4; ++ni) acc[mi][ni] = fzero;

  for (int kt = 0; kt < 8; ++kt) {
    __syncthreads();
#pragma unroll
    for (int j = 0; j < 4; ++j) {
      gll16(gA + (size_t)j * 8 * (DIM * 2), lA + j * 1024);
      gll16(gB + (size_t)j * 8 * (DIM * 2), lB + j * 1024);
    }
    gA += 128; gB += 128;
    __syncthreads();
#pragma unroll
    for (int c = 0; c < 8; c += 4) {                // logical chunk base (kk = c*8)
      const int po = ((c + jc) ^ cn7) << 3;         // swizzled element offset in row
      bf16x8 aF[4], bF[4];
#pragma unroll
      for (int mi = 0; mi < 4; ++mi)
        aF[mi] = *(const bf16x8*)&lsA[(wm * 64 + mi * 16 + cn) * 64 + po];
#pragma unroll
      for (int ni = 0; ni < 4; ++ni)
        bF[ni] = *(const bf16x8*)&lsB[(wn * 64 + ni * 16 + cn) * 64 + po];
#pragma unroll
      for (int mi = 0; mi < 4; ++mi)
#pragma unroll
        for (int ni = 0; ni < 4; ++ni)
          acc[mi][ni] = __builtin_amdgcn_mfma_f32_16x16x32_bf16(aF[mi], bF[ni], acc[mi][ni], 0, 0, 0);
    }
  }
  const int rq = (lane >> 4) * 4;
#pragma unroll
  for (int ni = 0; ni < 4; ++ni) {
    const int e = eBase + wn * 64 + ni * 16 + cn;
    const float bv = bvec[s * DIM + e];
#pragma unroll
    for (int mi = 0; mi < 4; ++mi)
#pragma unroll
      for (int r = 0; r < 4; ++r) {
        const int q = qBase + wm * 64 + mi * 16 + rq + r;
        tq[(size_t)s * (NQ * DIM) + (size_t)q * DIM + e] = f2bf(acc[mi][ni][r] + bv);
      }
  }
}

// ================= sq_q: 16 lanes per row, contiguous 256B per group-load =================
__global__ __launch_bounds__(256) void sqq_kernel(const ushort_t* __restrict__ tq,
                                                  float* __restrict__ sqq) {
  int tid = blockIdx.x * 256 + threadIdx.x;
  int row = tid >> 4;
  int sub = tid & 15;
  const uint4* rp = (const uint4*)(tq + (size_t)row * DIM);
  float ss = 0.f;
#pragma unroll
  for (int i = 0; i < 4; ++i) {
    uint4 v = rp[sub + i * 16];                     // 16 lanes x 16B contiguous
    uint32_t wsv[4] = {v.x, v.y, v.z, v.w};
#pragma unroll
    for (int j = 0; j < 4; ++j) {
      float lo = bf2f((ushort_t)(wsv[j] & 0xFFFFu));
      float hi = bf2f((ushort_t)(wsv[j] >> 16));
      ss += lo * lo + hi * hi;
    }
  }
#pragma unroll
  for (int off = 8; off; off >>= 1) ss += __shfl_xor(ss, off, 64);
  if (sub == 0) sqq[row] = ss;
}

// ================= GEMM2 fused dist/mean/std =================
// 64q x 128p tile, BK=64, global_load_lds + swizzle, 4 waves of 32x64. grid (64,8).
__global__ __launch_bounds__(256) void gemm_dist_kernel(const ushort_t* __restrict__ tq,
                                                        const ushort_t* __restrict__ pb,
                                                        const float* __restrict__ sqq,
                                                        const float* __restrict__ sqp,
                                                        float* __restrict__ out) {
  __shared__ __align__(16) ushort_t lsA[64 * 64];
  __shared__ __align__(16) ushort_t lsB[128 * 64];
  const int lane = threadIdx.x & 63;
  const int wave = threadIdx.x >> 6;
  const int wm = wave >> 1;            // q offset 32*wm
  const int wn = wave & 1;             // p offset 64*wn
  const int qBase = blockIdx.x * 64;
  const int pBase = blockIdx.y * 128;
  const int srow = lane >> 3;
  const int scol = ((lane & 7) ^ srow) * 16;        // swizzled global chunk (bytes)
  const char* gA = (const char*)tq + (size_t)(qBase + wave * 16 + srow) * (DIM * 2) + scol;
  const char* gB = (const char*)pb + (size_t)(pBase + wave * 32 + srow) * (DIM * 2) + scol;
  char* lA = (char*)&lsA[wave * 16 * 64];
  char* lB = (char*)&lsB[wave * 32 * 64];
  const int cn = lane & 15;
  const int cn7 = cn & 7;
  const int jc = lane >> 4;
  const int rq = (lane >> 4) * 4;
  const floatx4 fzero = {0.f, 0.f, 0.f, 0.f};

  float sum[2][4][4] = {};
  float ssq[2][4][4] = {};
  float sqp_v[4];
#pragma unroll
  for (int ni = 0; ni < 4; ++ni) sqp_v[ni] = sqp[pBase + wn * 64 + ni * 16 + cn];

  for (int s = 0; s < NS; ++s) {
    floatx4 acc[2][4];
#pragma unroll
    for (int mi = 0; mi < 2; ++mi)
#pragma unroll
      for (int ni = 0; ni < 4; ++ni) acc[mi][ni] = fzero;

    for (int kt = 0; kt < 8; ++kt) {
      __syncthreads();
      gll16(gA, lA);
      gll16(gA + (size_t)8 * (DIM * 2), lA + 1024);
#pragma unroll
      for (int j = 0; j < 4; ++j)
        gll16(gB + (size_t)j * 8 * (DIM * 2), lB + j * 1024);
      gA += 128; gB += 128;
      __syncthreads();
#pragma unroll
      for (int c = 0; c < 8; c += 4) {
        const int po = ((c + jc) ^ cn7) << 3;
        bf16x8 aF[2], bF[4];
#pragma unroll
        for (int mi = 0; mi < 2; ++mi)
          aF[mi] = *(const bf16x8*)&lsA[(wm * 32 + mi * 16 + cn) * 64 + po];
#pragma unroll
        for (int ni = 0; ni < 4; ++ni)
          bF[ni] = *(const bf16x8*)&lsB[(wn * 64 + ni * 16 + cn) * 64 + po];
#pragma unroll
        for (int mi = 0; mi < 2; ++mi)
#pragma unroll
          for (int ni = 0; ni < 4; ++ni)
            acc[mi][ni] = __builtin_amdgcn_mfma_f32_16x16x32_bf16(aF[mi], bF[ni], acc[mi][ni], 0, 0, 0);
      }
    }
    gA += (size_t)NQ * DIM * 2 - 1024;   // next sample, rewind k
    gB -= 1024;                           // rewind k
    // fold sample s into running stats
#pragma unroll
    for (int mi = 0; mi < 2; ++mi) {
      float4 aqv = *(const float4*)&sqq[s * NQ + qBase + wm * 32 + mi * 16 + rq];
      float aqa[4] = {aqv.x, aqv.y, aqv.z, aqv.w};
#pragma unroll
      for (int r = 0; r < 4; ++r) {
        float aq = aqa[r];
#pragma unroll
        for (int ni = 0; ni < 4; ++ni) {
          float c = acc[mi][ni][r];
          float dd = sqrtf(fmaxf(aq + sqp_v[ni] - 2.0f * c, 1e-12f));
          sum[mi][ni][r] += dd;
          ssq[mi][ni][r] += dd * dd;
        }
      }
    }
  }
#pragma unroll
  for (int mi = 0; mi < 2; ++mi)
#pragma unroll
    for (int ni = 0; ni < 4; ++ni)
#pragma unroll
      for (int r = 0; r < 4; ++r) {
        int q = qBase + wm * 32 + mi * 16 + rq + r;
        int p = pBase + wn * 64 + ni * 16 + cn;
        float sm = sum[mi][ni][r];
        float mean = sm * 0.1f;
        float var = (ssq[mi][ni][r] - sm * sm * 0.1f) * (1.0f / 9.0f);
        out[(size_t)q * NP + p] = mean;
        out[(size_t)NQ * NP + (size_t)q * NP + p] = sqrtf(fmaxf(var, 0.0f));
      }
}

// ================= launch =================
extern "C" void kernel_launch(void* const* d_in, const int* in_sizes, int n_in,
                              void* d_out, int out_size, void* d_ws, size_t ws_size,
                              hipStream_t stream) {
  const float* qf   = (const float*)d_in[0];
  const float* pf   = (const float*)d_in[1];
  const float* wmu  = (const float*)d_in[2];
  const float* wrho = (const float*)d_in[3];
  const float* bmu  = (const float*)d_in[4];
  const float* brho = (const float*)d_in[5];
  float* out = (float*)d_out;
  char* ws = (char*)d_ws;
  ushort_t* wt   = (ushort_t*)(ws);              //  5,242,880  W^T bf16 [s][e][k]
  ushort_t* qb   = (ushort_t*)(ws + 5242880);    //  4,194,304  query bf16
  ushort_t* pb   = (ushort_t*)(ws + 9437184);    //  1,048,576  proto bf16
  float*    bvec = (float*)   (ws + 10485760);   //     20,480  bias samples
  float*    sqp  = (float*)   (ws + 10506240);   //      4,096  ||p||^2
  ushort_t* tq   = (ushort_t*)(ws + 10510336);   // 41,943,040  tq bf16 [s][q][e]
  float*    sqq  = (float*)   (ws + 52453376);   //    163,840  ||tq||^2

  uint32_t kw0, kw1, kb0, kb1;
  threefry2x32(0u, 42u, 0u, 0u, &kw0, &kw1);
  threefry2x32(0u, 42u, 0u, 1u, &kb0, &kb1);

  hipLaunchKernelGGL(gen_w_kernel, dim3(10240), dim3(256), 0, stream, wmu, wrho, wt, kw0, kw1);
  hipLaunchKernelGGL(gen_b_kernel, dim3(20), dim3(256), 0, stream, bmu, brho, bvec, kb0, kb1);
  hipLaunchKernelGGL(cvt_q_kernel, dim3(2048), dim3(256), 0, stream, qf, qb);
  hipLaunchKernelGGL(cvt_p_sqp_kernel, dim3(1024), dim3(64), 0, stream, pf, pb, sqp);
  hipLaunchKernelGGL(gemm_tq_kernel, dim3(32, 4, 10), dim3(256), 0, stream, qb, wt, bvec, tq);
  hipLaunchKernelGGL(sqq_kernel, dim3(2560), dim3(256), 0, stream, tq, sqq);
  hipLaunchKernelGGL(gemm_dist_kernel, dim3(64, 8), dim3(256), 0, stream, tq, pb, sqq, sqp, out);
}

// Round 4
// 210.272 us; speedup vs baseline: 1.1920x; 1.0759x over previous
//
#include <hip/hip_runtime.h>
#include <stdint.h>

#define NS 10
#define DIM 512
#define NQ 4096
#define NP 1024

typedef unsigned short ushort_t;
typedef __bf16 bf16el_t;
typedef bf16el_t bf16x8 __attribute__((ext_vector_type(8)));
typedef float floatx4 __attribute__((ext_vector_type(4)));

// ================= threefry2x32-20 (JAX-compatible, partitionable path) =================
__host__ __device__ __forceinline__ uint32_t rotl32(uint32_t x, int r) {
  return (x << r) | (x >> (32 - r));
}

__host__ __device__ __forceinline__ void threefry2x32(uint32_t k0, uint32_t k1,
                                                      uint32_t x0, uint32_t x1,
                                                      uint32_t* o0, uint32_t* o1) {
  uint32_t ks2 = k0 ^ k1 ^ 0x1BD11BDAu;
  x0 += k0; x1 += k1;
#define TF_R(r) { x0 += x1; x1 = rotl32(x1, r); x1 ^= x0; }
  TF_R(13) TF_R(15) TF_R(26) TF_R(6)   x0 += k1;  x1 += ks2 + 1u;
  TF_R(17) TF_R(29) TF_R(16) TF_R(24)  x0 += ks2; x1 += k0 + 2u;
  TF_R(13) TF_R(15) TF_R(26) TF_R(6)   x0 += k0;  x1 += k1 + 3u;
  TF_R(17) TF_R(29) TF_R(16) TF_R(24)  x0 += k1;  x1 += ks2 + 4u;
  TF_R(13) TF_R(15) TF_R(26) TF_R(6)   x0 += ks2; x1 += k0 + 5u;
#undef TF_R
  *o0 = x0; *o1 = x1;
}

__device__ __forceinline__ uint32_t jax_random_bits(uint32_t k0, uint32_t k1, uint32_t idx) {
  uint32_t o0, o1;
  threefry2x32(k0, k1, 0u, idx, &o0, &o1);
  return o0 ^ o1;
}

// XLA ErfInv32 (Giles polynomial)
__device__ __forceinline__ float erfinvf_xla(float x) {
  float w = -log1pf(-x * x);
  float p;
  if (w < 5.0f) {
    w -= 2.5f;
    p = 2.81022636e-08f;
    p = fmaf(p, w, 3.43273939e-07f);
    p = fmaf(p, w, -3.5233877e-06f);
    p = fmaf(p, w, -4.39150654e-06f);
    p = fmaf(p, w, 0.00021858087f);
    p = fmaf(p, w, -0.00125372503f);
    p = fmaf(p, w, -0.00417768164f);
    p = fmaf(p, w, 0.246640727f);
    p = fmaf(p, w, 1.50140941f);
  } else {
    w = sqrtf(w) - 3.0f;
    p = -0.000200214257f;
    p = fmaf(p, w, 0.000100950558f);
    p = fmaf(p, w, 0.00134934322f);
    p = fmaf(p, w, -0.00367342844f);
    p = fmaf(p, w, 0.00573950773f);
    p = fmaf(p, w, -0.0076224613f);
    p = fmaf(p, w, 0.00943887047f);
    p = fmaf(p, w, 1.00167406f);
    p = fmaf(p, w, 2.83297682f);
  }
  return p * x;
}

__device__ __forceinline__ float jax_bits_to_normal(uint32_t bits) {
  float f = __uint_as_float((bits >> 9) | 0x3F800000u) - 1.0f;
  float u = f * 2.0f - 0.99999994f;
  u = fmaxf(u, -0.99999994f);
  return 1.41421356f * erfinvf_xla(u);
}

__device__ __forceinline__ float softplusf(float x) { return log1pf(expf(x)); }

__device__ __forceinline__ float bf2f(ushort_t u) {
  return __uint_as_float(((uint32_t)u) << 16);
}
__device__ __forceinline__ ushort_t f2bf(float f) {
  uint32_t u = __float_as_uint(f);
  u += 0x7FFFu + ((u >> 16) & 1u);
  return (ushort_t)(u >> 16);
}

// async global->LDS, 16B per lane. LDS dst = wave-uniform base + lane*16.
__device__ __forceinline__ void gll16(const void* g, void* l) {
  __builtin_amdgcn_global_load_lds(
      (const __attribute__((address_space(1))) uint32_t*)g,
      (__attribute__((address_space(3))) uint32_t*)l, 16, 0, 0);
}

// ================= gen_w: wt[s][e][k] = bf16(mu[k][e] + softplus(rho[k][e]) * eps[s][k][e]) =================
__global__ __launch_bounds__(256) void gen_w_kernel(const float* __restrict__ wmu,
                                                    const float* __restrict__ wrho,
                                                    ushort_t* __restrict__ wt,
                                                    uint32_t kw0, uint32_t kw1) {
  uint32_t tid = blockIdx.x * 256u + threadIdx.x;
  uint32_t s = tid >> 18;
  uint32_t r = tid & 0x3FFFFu;
  uint32_t e = r >> 9;
  uint32_t k = r & 511u;
  uint32_t eps_idx = (s << 18) | (k << 9) | e;      // JAX order [s][k][e]
  uint32_t bits = jax_random_bits(kw0, kw1, eps_idx);
  float n = jax_bits_to_normal(bits);
  uint32_t mi = (k << 9) | e;
  float w = wmu[mi] + softplusf(wrho[mi]) * n;
  wt[tid] = f2bf(w);
}

// ================= prep: cvt_q | cvt_p+sqp | gen_b | zero sqq  (fused by block range) ===========
__global__ __launch_bounds__(256) void prep_kernel(const float* __restrict__ qf,
                                                   const float* __restrict__ pf,
                                                   const float* __restrict__ bmu,
                                                   const float* __restrict__ brho,
                                                   ushort_t* __restrict__ qb,
                                                   ushort_t* __restrict__ pb,
                                                   float* __restrict__ sqp,
                                                   float* __restrict__ bvec,
                                                   float* __restrict__ sqq,
                                                   uint32_t kb0, uint32_t kb1) {
  const int blk = blockIdx.x;
  const int tid = threadIdx.x;
  if (blk < 2048) {                      // ---- cvt_q: 2,097,152 floats ----
    int i = (blk * 256 + tid) * 4;
    float4 v = *(const float4*)&qf[i];
    uint2 r;
    r.x = (uint32_t)f2bf(v.x) | ((uint32_t)f2bf(v.y) << 16);
    r.y = (uint32_t)f2bf(v.z) | ((uint32_t)f2bf(v.w) << 16);
    *(uint2*)&qb[i] = r;
  } else if (blk < 2304) {               // ---- cvt_p + sqp: 4 protos / block ----
    int p = (blk - 2048) * 4 + (tid >> 6);
    int lane = tid & 63;
    const float* src = pf + p * DIM + lane * 8;
    float4 a = *(const float4*)src;
    float4 b = *(const float4*)(src + 4);
    float vals[8] = {a.x, a.y, a.z, a.w, b.x, b.y, b.z, b.w};
    ushort_t o[8];
    float ss = 0.f;
#pragma unroll
    for (int i = 0; i < 8; ++i) {
      o[i] = f2bf(vals[i]);
      float f = bf2f(o[i]);
      ss += f * f;
    }
    *(uint4*)&pb[p * DIM + lane * 8] = *(const uint4*)o;
#pragma unroll
    for (int off = 32; off; off >>= 1) ss += __shfl_xor(ss, off, 64);
    if (lane == 0) sqp[p] = ss;
  } else if (blk < 2324) {               // ---- gen_b: 5120 ----
    uint32_t t2 = (blk - 2304) * 256u + tid;
    uint32_t e = t2 & 511u;
    uint32_t bits = jax_random_bits(kb0, kb1, t2);
    float n = jax_bits_to_normal(bits);
    bvec[t2] = bmu[e] + softplusf(brho[e]) * n;
  } else {                               // ---- zero sqq: 40960 floats ----
    int i = (blk - 2324) * 256 + tid;
    sqq[i] = 0.f;
  }
}

// ================= GEMM1: tq[s] = q @ W_s + b_s =================
// 128x128 tile, BK=64, global_load_lds + 8-chunk swizzle, 4 waves of 64x64. grid (32,4,10).
// Epilogue: LDS transpose -> coalesced dwordx4 bf16 stores + fused sqq atomics.
__global__ __launch_bounds__(256) void gemm_tq_kernel(const ushort_t* __restrict__ qb,
                                                      const ushort_t* __restrict__ wt,
                                                      const float* __restrict__ bvec,
                                                      ushort_t* __restrict__ tq,
                                                      float* __restrict__ sqq) {
  __shared__ __align__(16) ushort_t ls[2 * 128 * 64];   // 32 KB: lsA | lsB, reused by epilogue
  ushort_t* lsA = ls;
  ushort_t* lsB = ls + 128 * 64;
  const int lane = threadIdx.x & 63;
  const int wave = threadIdx.x >> 6;
  const int wm = wave >> 1, wn = wave & 1;   // 2x2 wave grid, 64x64 each
  const int qBase = blockIdx.x * 128;
  const int eBase = blockIdx.y * 128;
  const int s = blockIdx.z;
  const ushort_t* wbase = wt + (size_t)s * (DIM * DIM);  // [e][k]
  const int srow = lane >> 3;                       // 0..7
  const int scol = ((lane & 7) ^ srow) * 16;        // swizzled global chunk (bytes)
  const char* gA = (const char*)qb + (size_t)(qBase + wave * 32 + srow) * (DIM * 2) + scol;
  const char* gB = (const char*)wbase + (size_t)(eBase + wave * 32 + srow) * (DIM * 2) + scol;
  char* lA = (char*)&lsA[wave * 32 * 64];
  char* lB = (char*)&lsB[wave * 32 * 64];
  const int cn = lane & 15;
  const int cn7 = cn & 7;
  const int jc = lane >> 4;                         // 0..3
  const floatx4 fzero = {0.f, 0.f, 0.f, 0.f};
  floatx4 acc[4][4];
#pragma unroll
  for (int mi = 0; mi < 4; ++mi)
#pragma unroll
    for (int ni = 0; ni < 4; ++ni) acc[mi][ni] = fzero;

  for (int kt = 0; kt < 8; ++kt) {
    __syncthreads();
#pragma unroll
    for (int j = 0; j < 4; ++j) {
      gll16(gA + (size_t)j * 8 * (DIM * 2), lA + j * 1024);
      gll16(gB + (size_t)j * 8 * (DIM * 2), lB + j * 1024);
    }
    gA += 128; gB += 128;
    __syncthreads();
#pragma unroll
    for (int c = 0; c < 8; c += 4) {                // logical chunk base (kk = c*8)
      const int po = ((c + jc) ^ cn7) << 3;         // swizzled element offset in row
      bf16x8 aF[4], bF[4];
#pragma unroll
      for (int mi = 0; mi < 4; ++mi)
        aF[mi] = *(const bf16x8*)&lsA[(wm * 64 + mi * 16 + cn) * 64 + po];
#pragma unroll
      for (int ni = 0; ni < 4; ++ni)
        bF[ni] = *(const bf16x8*)&lsB[(wn * 64 + ni * 16 + cn) * 64 + po];
#pragma unroll
      for (int mi = 0; mi < 4; ++mi)
#pragma unroll
        for (int ni = 0; ni < 4; ++ni)
          acc[mi][ni] = __builtin_amdgcn_mfma_f32_16x16x32_bf16(aF[mi], bF[ni], acc[mi][ni], 0, 0, 0);
    }
  }

  // ---- epilogue: per-wave 64x64 transpose through LDS (swizzled), coalesced stores ----
  __syncthreads();                                  // everyone done reading lsA/lsB
  ushort_t* area = ls + wave * 4096;                // 8 KB/wave: 64 rows x 64 cols (row=128B=8 chunks)
  float bv[4];
#pragma unroll
  for (int ni = 0; ni < 4; ++ni) bv[ni] = bvec[s * DIM + eBase + wn * 64 + ni * 16 + cn];
  const int jc4 = jc * 4;
#pragma unroll
  for (int mi = 0; mi < 4; ++mi)
#pragma unroll
    for (int ni = 0; ni < 4; ++ni)
#pragma unroll
      for (int r = 0; r < 4; ++r) {
        const int lr = mi * 16 + jc4 + r;           // local q row
        const int lc = ni * 16 + cn;                // local e col
        const int off = lr * 64 + (((lc >> 3) ^ (lr & 7)) << 3) + (lc & 7);
        area[off] = f2bf(acc[mi][ni][r] + bv[ni]);
      }
  __syncthreads();
  const int rr = lane >> 3;                         // 0..7: row within pass
  const int ch = lane & 7;                          // e-chunk
  const int physc = ch ^ rr;                        // pass*8 == 0 mod 8 -> row&7 == rr
  const size_t tqs = (size_t)s * (NQ * DIM);
#pragma unroll
  for (int pass = 0; pass < 8; ++pass) {
    const int lr = pass * 8 + rr;
    uint4 v = *(const uint4*)&area[lr * 64 + physc * 8];
    uint32_t wsv[4] = {v.x, v.y, v.z, v.w};
    float ss = 0.f;
#pragma unroll
    for (int i = 0; i < 4; ++i) {
      float lo = bf2f((ushort_t)(wsv[i] & 0xFFFFu));
      float hi = bf2f((ushort_t)(wsv[i] >> 16));
      ss += lo * lo + hi * hi;
    }
    ss += __shfl_xor(ss, 1, 64);
    ss += __shfl_xor(ss, 2, 64);
    ss += __shfl_xor(ss, 4, 64);
    const int q = qBase + wm * 64 + lr;
    *(uint4*)&tq[tqs + (size_t)q * DIM + eBase + wn * 64 + ch * 8] = v;
    if (ch == 0) atomicAdd(&sqq[s * NQ + q], ss);
  }
}

// ================= GEMM2 fused dist/mean/std =================
// 64q x 128p tile, BK=128 (halved barriers), global_load_lds + 16-chunk swizzle,
// 4 waves of 32x64, s-loop inside. grid (64,8).
__global__ __launch_bounds__(256) void gemm_dist_kernel(const ushort_t* __restrict__ tq,
                                                        const ushort_t* __restrict__ pb,
                                                        const float* __restrict__ sqq,
                                                        const float* __restrict__ sqp,
                                                        float* __restrict__ out) {
  __shared__ __align__(16) ushort_t lsA[64 * 128];   // 16 KB, row = 256 B = 16 chunks
  __shared__ __align__(16) ushort_t lsB[128 * 128];  // 32 KB
  const int lane = threadIdx.x & 63;
  const int wave = threadIdx.x >> 6;
  const int wm = wave >> 1;            // q offset 32*wm
  const int wn = wave & 1;             // p offset 64*wn
  const int qBase = blockIdx.x * 64;
  const int pBase = blockIdx.y * 128;
  const int srow = lane >> 4;          // 0..3 (4 rows per gll call)
  const int scc = lane & 15;           // phys chunk 0..15
  const int sccx = scc ^ srow;         // base swizzled col (g=0)
  // A: wave stages rows wave*16 + g*4 + srow (g=0..3); B: wave*32 + g*4 + srow (g=0..7)
  const char* gA = (const char*)tq + (size_t)(qBase + wave * 16 + srow) * (DIM * 2);
  const char* gB = (const char*)pb + (size_t)(pBase + wave * 32 + srow) * (DIM * 2);
  char* lA = (char*)lsA + wave * 4096;  // 16 rows * 256 B
  char* lB = (char*)lsB + wave * 8192;  // 32 rows * 256 B
  const int cn = lane & 15;
  const int jc = lane >> 4;
  const int rq = jc * 4;
  const floatx4 fzero = {0.f, 0.f, 0.f, 0.f};

  float sum[2][4][4] = {};
  float ssq[2][4][4] = {};
  float sqp_v[4];
#pragma unroll
  for (int ni = 0; ni < 4; ++ni) sqp_v[ni] = sqp[pBase + wn * 64 + ni * 16 + cn];

  for (int s = 0; s < NS; ++s) {
    floatx4 acc[2][4];
#pragma unroll
    for (int mi = 0; mi < 2; ++mi)
#pragma unroll
      for (int ni = 0; ni < 4; ++ni) acc[mi][ni] = fzero;

    for (int kt = 0; kt < 4; ++kt) {   // K chunks of 128
      __syncthreads();
#pragma unroll
      for (int g = 0; g < 4; ++g)
        gll16(gA + (size_t)g * 4 * (DIM * 2) + ((sccx ^ (g * 4)) << 4), lA + g * 1024);
#pragma unroll
      for (int g = 0; g < 8; ++g)
        gll16(gB + (size_t)g * 4 * (DIM * 2) + ((sccx ^ ((g & 3) * 4)) << 4), lB + g * 1024);
      gA += 256; gB += 256;
      __syncthreads();
#pragma unroll
      for (int c4 = 0; c4 < 4; ++c4) {
        const int po = (((c4 * 4 + jc) ^ cn) & 15) << 3;   // swizzled element offset
        bf16x8 aF[2], bF[4];
#pragma unroll
        for (int mi = 0; mi < 2; ++mi)
          aF[mi] = *(const bf16x8*)&lsA[(wm * 32 + mi * 16 + cn) * 128 + po];
#pragma unroll
        for (int ni = 0; ni < 4; ++ni)
          bF[ni] = *(const bf16x8*)&lsB[(wn * 64 + ni * 16 + cn) * 128 + po];
#pragma unroll
        for (int mi = 0; mi < 2; ++mi)
#pragma unroll
          for (int ni = 0; ni < 4; ++ni)
            acc[mi][ni] = __builtin_amdgcn_mfma_f32_16x16x32_bf16(aF[mi], bF[ni], acc[mi][ni], 0, 0, 0);
      }
    }
    gA += (size_t)NQ * DIM * 2 - 1024;   // next sample, rewind K
    gB -= 1024;
    // fold sample s into running stats (ssq accumulates pre-sqrt sqd directly)
#pragma unroll
    for (int mi = 0; mi < 2; ++mi) {
      float4 aqv = *(const float4*)&sqq[s * NQ + qBase + wm * 32 + mi * 16 + rq];
      float aqa[4] = {aqv.x, aqv.y, aqv.z, aqv.w};
#pragma unroll
      for (int r = 0; r < 4; ++r) {
        float aq = aqa[r];
#pragma unroll
        for (int ni = 0; ni < 4; ++ni) {
          float sqd = fmaxf(fmaf(-2.0f, acc[mi][ni][r], aq + sqp_v[ni]), 1e-12f);
          sum[mi][ni][r] += sqrtf(sqd);
          ssq[mi][ni][r] += sqd;
        }
      }
    }
  }
#pragma unroll
  for (int mi = 0; mi < 2; ++mi)
#pragma unroll
    for (int ni = 0; ni < 4; ++ni)
#pragma unroll
      for (int r = 0; r < 4; ++r) {
        int q = qBase + wm * 32 + mi * 16 + rq + r;
        int p = pBase + wn * 64 + ni * 16 + cn;
        float sm = sum[mi][ni][r];
        float mean = sm * 0.1f;
        float var = (ssq[mi][ni][r] - sm * sm * 0.1f) * (1.0f / 9.0f);
        out[(size_t)q * NP + p] = mean;
        out[(size_t)NQ * NP + (size_t)q * NP + p] = sqrtf(fmaxf(var, 0.0f));
      }
}

// ================= launch =================
extern "C" void kernel_launch(void* const* d_in, const int* in_sizes, int n_in,
                              void* d_out, int out_size, void* d_ws, size_t ws_size,
                              hipStream_t stream) {
  const float* qf   = (const float*)d_in[0];
  const float* pf   = (const float*)d_in[1];
  const float* wmu  = (const float*)d_in[2];
  const float* wrho = (const float*)d_in[3];
  const float* bmu  = (const float*)d_in[4];
  const float* brho = (const float*)d_in[5];
  float* out = (float*)d_out;
  char* ws = (char*)d_ws;
  ushort_t* wt   = (ushort_t*)(ws);              //  5,242,880  W^T bf16 [s][e][k]
  ushort_t* qb   = (ushort_t*)(ws + 5242880);    //  4,194,304  query bf16
  ushort_t* pb   = (ushort_t*)(ws + 9437184);    //  1,048,576  proto bf16
  float*    bvec = (float*)   (ws + 10485760);   //     20,480  bias samples
  float*    sqp  = (float*)   (ws + 10506240);   //      4,096  ||p||^2
  ushort_t* tq   = (ushort_t*)(ws + 10510336);   // 41,943,040  tq bf16 [s][q][e]
  float*    sqq  = (float*)   (ws + 52453376);   //    163,840  ||tq||^2 (atomic-accumulated)

  uint32_t kw0, kw1, kb0, kb1;
  threefry2x32(0u, 42u, 0u, 0u, &kw0, &kw1);
  threefry2x32(0u, 42u, 0u, 1u, &kb0, &kb1);

  hipLaunchKernelGGL(gen_w_kernel, dim3(10240), dim3(256), 0, stream, wmu, wrho, wt, kw0, kw1);
  hipLaunchKernelGGL(prep_kernel, dim3(2484), dim3(256), 0, stream,
                     qf, pf, bmu, brho, qb, pb, sqp, bvec, sqq, kb0, kb1);
  hipLaunchKernelGGL(gemm_tq_kernel, dim3(32, 4, 10), dim3(256), 0, stream, qb, wt, bvec, tq, sqq);
  hipLaunchKernelGGL(gemm_dist_kernel, dim3(64, 8), dim3(256), 0, stream, tq, pb, sqq, sqp, out);
}